// Round 1
// baseline (386.033 us; speedup 1.0000x reference)
//
#include <hip/hip_runtime.h>
#include <cstdint>
#include <cstddef>

#define NF 256   // features
#define NG 512   // hidden (2F)
#define NC 64    // classes
#define NB 8192  // batch
#define NK 16    // active rules
#define BT 64    // batch tile

typedef __attribute__((ext_vector_type(8))) short short8;
typedef __attribute__((ext_vector_type(4))) float floatx4;

__device__ __forceinline__ unsigned short f2bf(float f) {
    union { float f; unsigned int u; } a; a.f = f;
    unsigned int u = a.u;
    u += 0x7fffu + ((u >> 16) & 1u);   // RNE
    return (unsigned short)(u >> 16);
}
__device__ __forceinline__ float bf2f(unsigned short s) {
    union { unsigned int u; float f; } a; a.u = ((unsigned int)s) << 16;
    return a.f;
}
__device__ __forceinline__ float elu1(float z) {
    return z > 0.0f ? z : (__expf(z) - 1.0f);
}

// ---------------- kernel 0: weights fp32 -> bf16 in workspace ----------------
// layout (ushort elements): [0,131072) W1b | [131072,262144) W2b | [262144,786432) Wcb
__global__ __launch_bounds__(256) void conv_kernel(
    const float* __restrict__ W1, const float* __restrict__ W2,
    const float* __restrict__ Wc, unsigned short* __restrict__ wb)
{
    int i = blockIdx.x * 256 + threadIdx.x;
    if (i < 131072)       wb[i] = f2bf(W1[i]);
    else if (i < 262144)  wb[i] = f2bf(W2[i - 131072]);
    else if (i < 786432)  wb[i] = f2bf(Wc[i - 262144]);
}

// ---------------- kernel 1: fused membership -> MLP -> fsi ----------------
// grid: 2048 blocks = 16 active rules x 128 batch tiles; 256 threads (4 waves)
// dynamic LDS: mv [64][264] bf16 (33792 B) + h1 [64][520] bf16 (66560 B) = 100352 B
__global__ __launch_bounds__(256) void fs_kernel(
    const float* __restrict__ x, const float* __restrict__ proto,
    const float* __restrict__ var, const unsigned short* __restrict__ W1b,
    const float* __restrict__ b1, const unsigned short* __restrict__ W2b,
    const float* __restrict__ b2, const float* __restrict__ W3,
    const float* __restrict__ b3, const int* __restrict__ ridx,
    float* __restrict__ fsi)
{
    extern __shared__ unsigned short smem[];
    unsigned short* mv = smem;              // [64][264]  (also reused for h2)
    unsigned short* h1 = smem + 64 * 264;   // [64][520]

    const int t    = threadIdx.x;
    const int kidx = blockIdx.x & 15;
    const int tile = blockIdx.x >> 4;
    const int r    = ridx[kidx];
    const int b0   = tile * BT;

    // ---- phase 0: membership mv = exp(-(x-p)^2 / (2 v^2)), v=clip(var,1e-4,0.1) ----
    {
        const int col   = (t & 63) * 4;
        const int rbase = t >> 6;
        const float4 p4 = *(const float4*)(proto + (size_t)r * NF + col);
        float4 v4 = *(const float4*)(var + (size_t)r * NF + col);
        float cx = fminf(fmaxf(v4.x, 1e-4f), 0.1f);
        float cy = fminf(fmaxf(v4.y, 1e-4f), 0.1f);
        float cz = fminf(fmaxf(v4.z, 1e-4f), 0.1f);
        float cw = fminf(fmaxf(v4.w, 1e-4f), 0.1f);
        float ix = 0.5f / (cx * cx), iy = 0.5f / (cy * cy);
        float iz = 0.5f / (cz * cz), iw = 0.5f / (cw * cw);
#pragma unroll
        for (int i = 0; i < 16; ++i) {
            int row = i * 4 + rbase;
            const float4 xv = *(const float4*)(x + (size_t)(b0 + row) * NF + col);
            float dx = xv.x - p4.x, dy = xv.y - p4.y, dz = xv.z - p4.z, dw = xv.w - p4.w;
            union { unsigned short s[4]; uint2 v; } pk;
            pk.s[0] = f2bf(__expf(-dx * dx * ix));
            pk.s[1] = f2bf(__expf(-dy * dy * iy));
            pk.s[2] = f2bf(__expf(-dz * dz * iz));
            pk.s[3] = f2bf(__expf(-dw * dw * iw));
            *(uint2*)(mv + row * 264 + col) = pk.v;
        }
    }
    __syncthreads();

    const int wave = t >> 6, lane = t & 63;
    const int ln = lane & 15, lq = lane >> 4;

    // ---- phase 1: h1 = ELU(mv @ W1^T + b1), wave tile 64x128 ----
    {
        const int nb = wave * 128;
        floatx4 acc[4][8];
#pragma unroll
        for (int mi = 0; mi < 4; ++mi)
#pragma unroll
            for (int ni = 0; ni < 8; ++ni) {
                floatx4 z = {0.0f, 0.0f, 0.0f, 0.0f};
                acc[mi][ni] = z;
            }
        for (int k0 = 0; k0 < NF; k0 += 32) {
            short8 a[4];
#pragma unroll
            for (int mi = 0; mi < 4; ++mi)
                a[mi] = *(const short8*)(mv + (mi * 16 + ln) * 264 + k0 + lq * 8);
#pragma unroll
            for (int ni = 0; ni < 8; ++ni) {
                short8 b = *(const short8*)(W1b + (size_t)(nb + ni * 16 + ln) * NF + k0 + lq * 8);
#pragma unroll
                for (int mi = 0; mi < 4; ++mi)
                    acc[mi][ni] = __builtin_amdgcn_mfma_f32_16x16x32_bf16(a[mi], b, acc[mi][ni], 0, 0, 0);
            }
        }
#pragma unroll
        for (int ni = 0; ni < 8; ++ni) {
            int n = nb + ni * 16 + ln;
            float bias = b1[n];
#pragma unroll
            for (int mi = 0; mi < 4; ++mi)
#pragma unroll
                for (int rg = 0; rg < 4; ++rg) {
                    float z = acc[mi][ni][rg] + bias;
                    h1[(mi * 16 + lq * 4 + rg) * 520 + n] = f2bf(elu1(z));
                }
        }
    }
    __syncthreads();

    // ---- phase 2: h2 = ELU(h1 @ W2^T + b2) -> into mv region, wave tile 64x64 ----
    {
        const int nb = wave * 64;
        floatx4 acc[4][4];
#pragma unroll
        for (int mi = 0; mi < 4; ++mi)
#pragma unroll
            for (int ni = 0; ni < 4; ++ni) {
                floatx4 z = {0.0f, 0.0f, 0.0f, 0.0f};
                acc[mi][ni] = z;
            }
        for (int k0 = 0; k0 < NG; k0 += 32) {
            short8 a[4];
#pragma unroll
            for (int mi = 0; mi < 4; ++mi)
                a[mi] = *(const short8*)(h1 + (mi * 16 + ln) * 520 + k0 + lq * 8);
#pragma unroll
            for (int ni = 0; ni < 4; ++ni) {
                short8 b = *(const short8*)(W2b + (size_t)(nb + ni * 16 + ln) * NG + k0 + lq * 8);
#pragma unroll
                for (int mi = 0; mi < 4; ++mi)
                    acc[mi][ni] = __builtin_amdgcn_mfma_f32_16x16x32_bf16(a[mi], b, acc[mi][ni], 0, 0, 0);
            }
        }
        // writes go to mv region (disjoint from h1 reads of other waves)
#pragma unroll
        for (int ni = 0; ni < 4; ++ni) {
            int n = nb + ni * 16 + ln;
            float bias = b2[n];
#pragma unroll
            for (int mi = 0; mi < 4; ++mi)
#pragma unroll
                for (int rg = 0; rg < 4; ++rg) {
                    float z = acc[mi][ni][rg] + bias;
                    mv[(mi * 16 + lq * 4 + rg) * 264 + n] = f2bf(elu1(z));
                }
        }
    }
    __syncthreads();

    // ---- phase 3: fsi[b] = h2[b,:] . W3 + b3 ----
    {
        const int row = t >> 2, q = t & 3;
        float s = 0.0f;
#pragma unroll
        for (int j = 0; j < 64; j += 4) {
            int f = q * 64 + j;
            union { uint2 v; unsigned short s[4]; } pk;
            pk.v = *(const uint2*)(mv + row * 264 + f);
            const float4 w = *(const float4*)(W3 + f);
            s += bf2f(pk.s[0]) * w.x + bf2f(pk.s[1]) * w.y +
                 bf2f(pk.s[2]) * w.z + bf2f(pk.s[3]) * w.w;
        }
        s += __shfl_xor(s, 1);
        s += __shfl_xor(s, 2);
        if (q == 0) fsi[(size_t)kidx * NB + b0 + row] = s + b3[0];
    }
}

// ---------------- kernel 2: softmax over rules + consequent + weighted sum ----------------
// grid: 128 blocks x 256 threads; each block = 64 batch rows
__global__ __launch_bounds__(256) void cons_kernel(
    const float* __restrict__ x, const unsigned short* __restrict__ Wcb,
    const float* __restrict__ bc, const float* __restrict__ fsi,
    const int* __restrict__ ridx, float* __restrict__ outp,
    float* __restrict__ fire_out)
{
    __shared__ unsigned short xl[BT * 264];
    __shared__ float fire[BT][NK];

    const int t  = threadIdx.x;
    const int b0 = blockIdx.x * BT;

    // x -> bf16 LDS
    {
        const int col   = (t & 63) * 4;
        const int rbase = t >> 6;
#pragma unroll
        for (int i = 0; i < 16; ++i) {
            int row = i * 4 + rbase;
            const float4 xv = *(const float4*)(x + (size_t)(b0 + row) * NF + col);
            union { unsigned short s[4]; uint2 v; } pk;
            pk.s[0] = f2bf(xv.x); pk.s[1] = f2bf(xv.y);
            pk.s[2] = f2bf(xv.z); pk.s[3] = f2bf(xv.w);
            *(uint2*)(xl + row * 264 + col) = pk.v;
        }
    }
    // softmax over the 16 active rules (one thread per batch row)
    if (t < BT) {
        float v[NK]; float mx = -1e30f;
#pragma unroll
        for (int k = 0; k < NK; ++k) { v[k] = fsi[(size_t)k * NB + b0 + t]; mx = fmaxf(mx, v[k]); }
        float sum = 0.0f;
#pragma unroll
        for (int k = 0; k < NK; ++k) { v[k] = __expf(v[k] - mx); sum += v[k]; }
        float inv = 1.0f / sum;
#pragma unroll
        for (int k = 0; k < NK; ++k) fire[t][k] = v[k] * inv;
    }
    __syncthreads();

    // write fire_strength output [B][16]
    for (int i = t; i < BT * NK; i += 256)
        fire_out[(size_t)b0 * NK + i] = fire[i >> 4][i & 15];

    // consequent: out[b,c] = sum_k fire[b,k] * relu(x[b,:] . Wc[r_k][c,:] + bc[r_k][c])
    const int wave = t >> 6, lane = t & 63;
    const int ln = lane & 15, lq = lane >> 4;
    const int mrow = wave * 16;

    floatx4 oacc[4];
#pragma unroll
    for (int ni = 0; ni < 4; ++ni) {
        floatx4 z = {0.0f, 0.0f, 0.0f, 0.0f};
        oacc[ni] = z;
    }
    for (int k = 0; k < NK; ++k) {
        int r = ridx[k];
        const unsigned short* Wr = Wcb + (size_t)r * NC * NF;
        floatx4 acc[4];
#pragma unroll
        for (int ni = 0; ni < 4; ++ni) {
            floatx4 z = {0.0f, 0.0f, 0.0f, 0.0f};
            acc[ni] = z;
        }
#pragma unroll
        for (int k0 = 0; k0 < NF; k0 += 32) {
            short8 a = *(const short8*)(xl + (mrow + ln) * 264 + k0 + lq * 8);
#pragma unroll
            for (int ni = 0; ni < 4; ++ni) {
                short8 b = *(const short8*)(Wr + (size_t)(ni * 16 + ln) * NF + k0 + lq * 8);
                acc[ni] = __builtin_amdgcn_mfma_f32_16x16x32_bf16(a, b, acc[ni], 0, 0, 0);
            }
        }
        float fv[4];
#pragma unroll
        for (int rg = 0; rg < 4; ++rg) fv[rg] = fire[mrow + lq * 4 + rg][k];
#pragma unroll
        for (int ni = 0; ni < 4; ++ni) {
            float bias = bc[(size_t)r * NC + ni * 16 + ln];
#pragma unroll
            for (int rg = 0; rg < 4; ++rg) {
                float z = fmaxf(acc[ni][rg] + bias, 0.0f);
                oacc[ni][rg] += z * fv[rg];
            }
        }
    }
#pragma unroll
    for (int ni = 0; ni < 4; ++ni)
#pragma unroll
        for (int rg = 0; rg < 4; ++rg)
            outp[(size_t)(b0 + mrow + lq * 4 + rg) * NC + ni * 16 + ln] = oacc[ni][rg];
}

extern "C" void kernel_launch(void* const* d_in, const int* in_sizes, int n_in,
                              void* d_out, int out_size, void* d_ws, size_t ws_size,
                              hipStream_t stream)
{
    (void)in_sizes; (void)n_in; (void)out_size;
    if (ws_size < 2097152) return;  // need 1.5MB bf16 weights + 0.5MB fsi

    const float* x     = (const float*)d_in[0];
    const float* proto = (const float*)d_in[1];
    const float* var   = (const float*)d_in[2];
    const float* W1    = (const float*)d_in[3];
    const float* b1    = (const float*)d_in[4];
    const float* W2    = (const float*)d_in[5];
    const float* b2    = (const float*)d_in[6];
    const float* W3    = (const float*)d_in[7];
    const float* b3    = (const float*)d_in[8];
    const float* Wc    = (const float*)d_in[9];
    const float* bc    = (const float*)d_in[10];
    const int*   ridx  = (const int*)d_in[11];

    unsigned short* wb  = (unsigned short*)d_ws;
    unsigned short* W1b = wb;                 // 131072
    unsigned short* W2b = wb + 131072;        // 131072
    unsigned short* Wcb = wb + 262144;        // 524288
    float* fsi = (float*)((char*)d_ws + (size_t)786432 * 2);  // 16*8192 floats

    float* outp     = (float*)d_out;
    float* fire_out = outp + (size_t)NB * NC;

    conv_kernel<<<3072, 256, 0, stream>>>(W1, W2, Wc, wb);

    const int fs_lds = 64 * 264 * 2 + 64 * 520 * 2;  // 100352 B
    hipFuncSetAttribute((const void*)fs_kernel,
                        hipFuncAttributeMaxDynamicSharedMemorySize, fs_lds);
    fs_kernel<<<2048, 256, fs_lds, stream>>>(x, proto, var, W1b, b1, W2b, b2,
                                             W3, b3, ridx, fsi);
    cons_kernel<<<128, 256, 0, stream>>>(x, Wcb, bc, fsi, ridx, outp, fire_out);
}

// Round 2
// 254.778 us; speedup vs baseline: 1.5152x; 1.5152x over previous
//
#include <hip/hip_runtime.h>
#include <cstdint>
#include <cstddef>

#define NF 256   // features
#define NG 512   // hidden (2F)
#define NC 64    // classes
#define NB 8192  // batch
#define NK 16    // active rules
#define BT 64    // fs batch tile

typedef __attribute__((ext_vector_type(8))) short short8;
typedef __attribute__((ext_vector_type(4))) float floatx4;

__device__ __forceinline__ unsigned short f2bf(float f) {
    union { float f; unsigned int u; } a; a.f = f;
    unsigned int u = a.u;
    u += 0x7fffu + ((u >> 16) & 1u);   // RNE
    return (unsigned short)(u >> 16);
}
__device__ __forceinline__ float elu1(float z) {
    return z > 0.0f ? z : (__expf(z) - 1.0f);
}

// ---------------- kernel 0: weights fp32 -> bf16 in workspace ----------------
// layout (ushort elements): [0,131072) W1b | [131072,262144) W2b | [262144,786432) Wcb
__global__ __launch_bounds__(256) void conv_kernel(
    const float* __restrict__ W1, const float* __restrict__ W2,
    const float* __restrict__ Wc, unsigned short* __restrict__ wb)
{
    int i = blockIdx.x * 256 + threadIdx.x;
    if (i < 131072)       wb[i] = f2bf(W1[i]);
    else if (i < 262144)  wb[i] = f2bf(W2[i - 131072]);
    else if (i < 786432)  wb[i] = f2bf(Wc[i - 262144]);
}

// ---------------- kernel 1: fused membership -> MLP -> fsi ----------------
// grid: 2048 blocks = 16 active rules x 128 batch tiles; 512 threads (8 waves)
// dynamic LDS: mv [64][264] bf16 (33792 B) + chunk buf [64][264] bf16 (33792 B)
//   = 67584 B -> 2 blocks/CU (16 waves/CU) with VGPR capped at 128 via
//   __launch_bounds__(512,4).
// h1 [64][512] is never fully materialized: computed in 2 chunks of 256 cols,
// phase-2 contraction accumulated across chunks in registers.
__global__ __launch_bounds__(512, 4) void fs_kernel(
    const float* __restrict__ x, const float* __restrict__ proto,
    const float* __restrict__ var, const unsigned short* __restrict__ W1b,
    const float* __restrict__ b1, const unsigned short* __restrict__ W2b,
    const float* __restrict__ b2, const float* __restrict__ W3,
    const float* __restrict__ b3, const int* __restrict__ ridx,
    float* __restrict__ fsi)
{
    extern __shared__ unsigned short smem[];
    unsigned short* mv = smem;              // [64][264]
    unsigned short* cb = smem + 64 * 264;   // [64][264] chunk buffer (reused; also part[] later)

    const int t    = threadIdx.x;
    const int kidx = blockIdx.x & 15;
    const int tile = blockIdx.x >> 4;
    const int r    = ridx[kidx];
    const int b0   = tile * BT;

    // ---- phase 0: membership mv = exp(-(x-p)^2 / (2 v^2)), v=clip(var,1e-4,0.1) ----
    {
        const int col   = (t & 63) * 4;
        const int rbase = t >> 6;           // 0..7
        const float4 p4 = *(const float4*)(proto + (size_t)r * NF + col);
        float4 v4 = *(const float4*)(var + (size_t)r * NF + col);
        float cx = fminf(fmaxf(v4.x, 1e-4f), 0.1f);
        float cy = fminf(fmaxf(v4.y, 1e-4f), 0.1f);
        float cz = fminf(fmaxf(v4.z, 1e-4f), 0.1f);
        float cw = fminf(fmaxf(v4.w, 1e-4f), 0.1f);
        float ix = 0.5f / (cx * cx), iy = 0.5f / (cy * cy);
        float iz = 0.5f / (cz * cz), iw = 0.5f / (cw * cw);
#pragma unroll
        for (int i = 0; i < 8; ++i) {
            int row = i * 8 + rbase;
            const float4 xv = *(const float4*)(x + (size_t)(b0 + row) * NF + col);
            float dx = xv.x - p4.x, dy = xv.y - p4.y, dz = xv.z - p4.z, dw = xv.w - p4.w;
            union { unsigned short s[4]; uint2 v; } pk;
            pk.s[0] = f2bf(__expf(-dx * dx * ix));
            pk.s[1] = f2bf(__expf(-dy * dy * iy));
            pk.s[2] = f2bf(__expf(-dz * dz * iz));
            pk.s[3] = f2bf(__expf(-dw * dw * iw));
            *(uint2*)(mv + row * 264 + col) = pk.v;
        }
    }
    __syncthreads();

    const int wave = t >> 6, lane = t & 63;
    const int ln = lane & 15, lq = lane >> 4;

    // persistent h2 accumulator: wave's N-tile = 32 cols (8 waves x 32 = 256)
    floatx4 acc2[4][2];
#pragma unroll
    for (int mi = 0; mi < 4; ++mi)
#pragma unroll
        for (int ni = 0; ni < 2; ++ni) {
            floatx4 z = {0.0f, 0.0f, 0.0f, 0.0f};
            acc2[mi][ni] = z;
        }

    for (int c = 0; c < 2; ++c) {
        // ---- phase 1 (chunk c): h1 cols [c*256, c*256+256) ----
        // wave's N-subtile: 32 cols of the chunk
        floatx4 acc1[4][2];
#pragma unroll
        for (int mi = 0; mi < 4; ++mi)
#pragma unroll
            for (int ni = 0; ni < 2; ++ni) {
                floatx4 z = {0.0f, 0.0f, 0.0f, 0.0f};
                acc1[mi][ni] = z;
            }
        const int nbase = c * 256 + wave * 32;
#pragma unroll
        for (int k0 = 0; k0 < NF; k0 += 32) {
            short8 a[4];
#pragma unroll
            for (int mi = 0; mi < 4; ++mi)
                a[mi] = *(const short8*)(mv + (mi * 16 + ln) * 264 + k0 + lq * 8);
#pragma unroll
            for (int ni = 0; ni < 2; ++ni) {
                short8 b = *(const short8*)(W1b + (size_t)(nbase + ni * 16 + ln) * NF + k0 + lq * 8);
#pragma unroll
                for (int mi = 0; mi < 4; ++mi)
                    acc1[mi][ni] = __builtin_amdgcn_mfma_f32_16x16x32_bf16(a[mi], b, acc1[mi][ni], 0, 0, 0);
            }
        }
        __syncthreads();   // prior chunk's phase-2 reads of cb are done
        // ELU + bias, write chunk to LDS (chunk-local col = wave*32 + ni*16 + ln)
#pragma unroll
        for (int ni = 0; ni < 2; ++ni) {
            int n = nbase + ni * 16 + ln;
            float bias = b1[n];
            int ccol = wave * 32 + ni * 16 + ln;
#pragma unroll
            for (int mi = 0; mi < 4; ++mi)
#pragma unroll
                for (int rg = 0; rg < 4; ++rg) {
                    float z = acc1[mi][ni][rg] + bias;
                    cb[(mi * 16 + lq * 4 + rg) * 264 + ccol] = f2bf(elu1(z));
                }
        }
        __syncthreads();
        // ---- phase 2 (chunk c): acc2 += cb @ W2[:, c*256 : c*256+256]^T ----
#pragma unroll
        for (int k0 = 0; k0 < 256; k0 += 32) {
            short8 a[4];
#pragma unroll
            for (int mi = 0; mi < 4; ++mi)
                a[mi] = *(const short8*)(cb + (mi * 16 + ln) * 264 + k0 + lq * 8);
#pragma unroll
            for (int ni = 0; ni < 2; ++ni) {
                short8 b = *(const short8*)(W2b + (size_t)(wave * 32 + ni * 16 + ln) * NG + c * 256 + k0 + lq * 8);
#pragma unroll
                for (int mi = 0; mi < 4; ++mi)
                    acc2[mi][ni] = __builtin_amdgcn_mfma_f32_16x16x32_bf16(a[mi], b, acc2[mi][ni], 0, 0, 0);
            }
        }
    }

    // ---- phase 3: fsi[b] = ELU(h2)[b,:] . W3 + b3 (h2 in registers, fp32) ----
    __syncthreads();                 // cb reads done; reuse cb as float part[8][64]
    float* part = (float*)cb;
    float bb[2], ww[2];
#pragma unroll
    for (int ni = 0; ni < 2; ++ni) {
        int n = wave * 32 + ni * 16 + ln;
        bb[ni] = b2[n];
        ww[ni] = W3[n];
    }
#pragma unroll
    for (int mi = 0; mi < 4; ++mi)
#pragma unroll
        for (int rg = 0; rg < 4; ++rg) {
            float s = elu1(acc2[mi][0][rg] + bb[0]) * ww[0]
                    + elu1(acc2[mi][1][rg] + bb[1]) * ww[1];
            s += __shfl_xor(s, 1);
            s += __shfl_xor(s, 2);
            s += __shfl_xor(s, 4);
            s += __shfl_xor(s, 8);
            if (ln == 0) part[wave * 64 + mi * 16 + lq * 4 + rg] = s;
        }
    __syncthreads();
    if (t < 64) {
        float s = b3[0];
#pragma unroll
        for (int w = 0; w < 8; ++w) s += part[w * 64 + t];
        fsi[(size_t)kidx * NB + b0 + t] = s;
    }
}

// ---------------- kernel 2: softmax over rules + consequent + weighted sum ----------------
// grid: 512 blocks x 256 threads; each block = 16 batch rows, wave w = 16 classes
__global__ __launch_bounds__(256) void cons_kernel(
    const float* __restrict__ x, const unsigned short* __restrict__ Wcb,
    const float* __restrict__ bc, const float* __restrict__ fsi,
    const int* __restrict__ ridx, float* __restrict__ outp,
    float* __restrict__ fire_out)
{
    __shared__ unsigned short xl[16 * 264];
    __shared__ float fire[16][NK];

    const int t  = threadIdx.x;
    const int b0 = blockIdx.x * 16;

    // x -> bf16 LDS (16 rows)
    {
        const int col   = (t & 63) * 4;
        const int rbase = t >> 6;   // 0..3
#pragma unroll
        for (int i = 0; i < 4; ++i) {
            int row = i * 4 + rbase;
            const float4 xv = *(const float4*)(x + (size_t)(b0 + row) * NF + col);
            union { unsigned short s[4]; uint2 v; } pk;
            pk.s[0] = f2bf(xv.x); pk.s[1] = f2bf(xv.y);
            pk.s[2] = f2bf(xv.z); pk.s[3] = f2bf(xv.w);
            *(uint2*)(xl + row * 264 + col) = pk.v;
        }
    }
    // softmax over 16 rules, fully parallel: thread = (row = t>>4, k = t&15)
    {
        const int row = t >> 4, k = t & 15;
        float v = fsi[(size_t)k * NB + b0 + row];
        float mx = v;
        mx = fmaxf(mx, __shfl_xor(mx, 1));
        mx = fmaxf(mx, __shfl_xor(mx, 2));
        mx = fmaxf(mx, __shfl_xor(mx, 4));
        mx = fmaxf(mx, __shfl_xor(mx, 8));
        float e = __expf(v - mx);
        float sum = e;
        sum += __shfl_xor(sum, 1);
        sum += __shfl_xor(sum, 2);
        sum += __shfl_xor(sum, 4);
        sum += __shfl_xor(sum, 8);
        float fv = e / sum;
        fire[row][k] = fv;
        fire_out[(size_t)b0 * NK + t] = fv;   // (b0+row)*16 + k == b0*16 + t
    }
    __syncthreads();

    // consequent: wave w covers classes [w*16, w*16+16), all 16 rows
    const int wave = t >> 6, lane = t & 63;
    const int ln = lane & 15, lq = lane >> 4;
    const int nb = wave * 16;

    // A-fragments (x tile) cached in registers, reused across all 16 rules
    short8 afr[8];
#pragma unroll
    for (int k0i = 0; k0i < 8; ++k0i)
        afr[k0i] = *(const short8*)(xl + ln * 264 + k0i * 32 + lq * 8);

    floatx4 oacc = {0.0f, 0.0f, 0.0f, 0.0f};
    for (int k = 0; k < NK; ++k) {
        int r = ridx[k];
        const unsigned short* Wr = Wcb + ((size_t)r * NC + nb) * NF;
        floatx4 acc = {0.0f, 0.0f, 0.0f, 0.0f};
#pragma unroll
        for (int k0i = 0; k0i < 8; ++k0i) {
            short8 b = *(const short8*)(Wr + (size_t)ln * NF + k0i * 32 + lq * 8);
            acc = __builtin_amdgcn_mfma_f32_16x16x32_bf16(afr[k0i], b, acc, 0, 0, 0);
        }
        float bias = bc[(size_t)r * NC + nb + ln];
#pragma unroll
        for (int rg = 0; rg < 4; ++rg) {
            float z = fmaxf(acc[rg] + bias, 0.0f);
            oacc[rg] += z * fire[lq * 4 + rg][k];
        }
    }
#pragma unroll
    for (int rg = 0; rg < 4; ++rg)
        outp[(size_t)(b0 + lq * 4 + rg) * NC + nb + ln] = oacc[rg];
}

extern "C" void kernel_launch(void* const* d_in, const int* in_sizes, int n_in,
                              void* d_out, int out_size, void* d_ws, size_t ws_size,
                              hipStream_t stream)
{
    (void)in_sizes; (void)n_in; (void)out_size;
    if (ws_size < 2097152) return;  // 1.5MB bf16 weights + 0.5MB fsi

    const float* x     = (const float*)d_in[0];
    const float* proto = (const float*)d_in[1];
    const float* var   = (const float*)d_in[2];
    const float* W1    = (const float*)d_in[3];
    const float* b1    = (const float*)d_in[4];
    const float* W2    = (const float*)d_in[5];
    const float* b2    = (const float*)d_in[6];
    const float* W3    = (const float*)d_in[7];
    const float* b3    = (const float*)d_in[8];
    const float* Wc    = (const float*)d_in[9];
    const float* bc    = (const float*)d_in[10];
    const int*   ridx  = (const int*)d_in[11];

    unsigned short* wb  = (unsigned short*)d_ws;
    unsigned short* W1b = wb;                 // 131072
    unsigned short* W2b = wb + 131072;        // 131072
    unsigned short* Wcb = wb + 262144;        // 524288
    float* fsi = (float*)((char*)d_ws + (size_t)786432 * 2);  // 16*8192 floats

    float* outp     = (float*)d_out;
    float* fire_out = outp + (size_t)NB * NC;

    conv_kernel<<<3072, 256, 0, stream>>>(W1, W2, Wc, wb);

    const int fs_lds = 2 * 64 * 264 * 2;  // 67584 B
    hipFuncSetAttribute((const void*)fs_kernel,
                        hipFuncAttributeMaxDynamicSharedMemorySize, fs_lds);
    fs_kernel<<<2048, 512, fs_lds, stream>>>(x, proto, var, W1b, b1, W2b, b2,
                                             W3, b3, ridx, fsi);
    cons_kernel<<<512, 256, 0, stream>>>(x, Wcb, bc, fsi, ridx, outp, fire_out);
}